// Round 13
// baseline (310.832 us; speedup 1.0000x reference)
//
#include <hip/hip_runtime.h>
#include <hip/hip_bf16.h>

// GraphSAGE 2-layer forward.
// R13: revert R12's degree-perm (regressed gather_h 67->78: scattered csr/r/h
// locality beat the divergence win). De-slab all tables (slabbing proven
// neutral in R6; single-pass gathers read csr once per edge). FULLY SPLIT
// dispatches for profiling visibility: the ~110us unaccounted gap between the
// byte model (~175us) and measured (289us) must be located before further
// optimization.

#define THREADS 256
#define NBLK1 512          // csr part1 blocks (chunk = 3125 <= 3328 stage cap)
#define BCAP 12288         // finalize LDS pair capacity (bucket mean 8192)

typedef __bf16 bf16x8 __attribute__((ext_vector_type(8)));
typedef float floatx4 __attribute__((ext_vector_type(4)));
typedef float f32x4 __attribute__((ext_vector_type(4)));
typedef unsigned int u32x4 __attribute__((ext_vector_type(4)));

union ABfrag { bf16x8 v; unsigned short u[8]; uint4 q; };
union V4 { u32x4 w; uint4 q; };

static __device__ __forceinline__ unsigned short f2bf(float f) {
    unsigned int u = __float_as_uint(f);
    u = (u + 0x7fffu + ((u >> 16) & 1u)) >> 16;   // RNE
    return (unsigned short)u;
}

static __device__ __forceinline__ void unpack8(float* o, uint4 v) {
    o[0] = __uint_as_float(v.x << 16);
    o[1] = __uint_as_float(v.x & 0xffff0000u);
    o[2] = __uint_as_float(v.y << 16);
    o[3] = __uint_as_float(v.y & 0xffff0000u);
    o[4] = __uint_as_float(v.z << 16);
    o[5] = __uint_as_float(v.z & 0xffff0000u);
    o[6] = __uint_as_float(v.w << 16);
    o[7] = __uint_as_float(v.w & 0xffff0000u);
}

static __device__ __forceinline__ void acc8(float* acc, uint4 v) {
    float t[8];
    unpack8(t, v);
    #pragma unroll
    for (int i = 0; i < 8; ++i) acc[i] += t[i];
}

// ---------------------------------------------------------------------------
// D1: cast x and the 4 weight matrices to bf16.
__global__ __launch_bounds__(THREADS)
void cast_xw(const float* __restrict__ x, const float* __restrict__ wa,
             const float* __restrict__ wb, const float* __restrict__ wc,
             const float* __restrict__ wd, unsigned short* __restrict__ xb,
             unsigned short* __restrict__ Wb, int nx4) {
    int i = blockIdx.x * THREADS + threadIdx.x;
    if (i < nx4) {
        float4 v = ((const float4*)x)[i];
        ushort4 u;
        u.x = f2bf(v.x); u.y = f2bf(v.y); u.z = f2bf(v.z); u.w = f2bf(v.w);
        ((ushort4*)xb)[i] = u;
        return;
    }
    int j = i - nx4;
    if (j >= 49152) return;
    float v;
    if (j < 16384) v = wa[j];
    else if (j < 32768) v = wb[j - 16384];
    else if (j < 40960) v = wc[j - 32768];
    else v = wd[j - 40960];
    Wb[j] = f2bf(v);
}

// ---------------------------------------------------------------------------
// D2: CSR part1 — per-chunk LDS bucket sort, coalesced pair output,
// (base<<16|count) records, totals atomics. [R9-proven]
__global__ __launch_bounds__(THREADS)
void csr_part1(const int* __restrict__ src, const int* __restrict__ dst,
               unsigned int* __restrict__ pairs, unsigned int* __restrict__ counts,
               int* __restrict__ totals, int E, int chunk, int NB) {
    __shared__ int lh[THREADS], lsc[THREADS], lpos[THREADS];
    __shared__ unsigned int stage[3328];
    int t = threadIdx.x;
    int e0 = blockIdx.x * chunk, e1 = min(E, e0 + chunk);
    lh[t] = 0;
    __syncthreads();
    for (int e = e0 + t; e < e1; e += THREADS) atomicAdd(&lh[dst[e] >> 8], 1);
    __syncthreads();
    int v = lh[t];
    lsc[t] = v;
    __syncthreads();
    for (int off = 1; off < THREADS; off <<= 1) {
        int tv = (t >= off) ? lsc[t - off] : 0;
        __syncthreads();
        lsc[t] += tv;
        __syncthreads();
    }
    int base = lsc[t] - v;
    lpos[t] = base;
    __syncthreads();
    for (int e = e0 + t; e < e1; e += THREADS) {
        int dd = dst[e];
        int p = atomicAdd(&lpos[dd >> 8], 1);
        stage[p] = (unsigned int)src[e] | ((unsigned int)(dd & 255) << 16);
    }
    __syncthreads();
    int n = e1 - e0;
    for (int i = t; i < n; i += THREADS) pairs[e0 + i] = stage[i];
    if (t < NB) {
        counts[(size_t)blockIdx.x * 256 + t] = ((unsigned int)base << 16) | (unsigned int)v;
        if (v) atomicAdd(&totals[t], v);
    }
}

// ---------------------------------------------------------------------------
// MFMA bf16 GEMM body: one wave per 16-row M-tile, K=128, 64 cols per job,
// B-frags VGPR-resident from pre-cast bf16 W. A bf16 row-major [row][128].
// Outputs ROW-MAJOR [row][NOUT], bf16. NOUT=128: jobs 0,1 -> p halves;
// 2,3 -> r halves. NOUT=64: job 0 -> p, 1 -> r.
template<int NOUT>
static __device__ __forceinline__
void gemm_body(const unsigned short* __restrict__ A, const unsigned short* __restrict__ W0,
               const unsigned short* __restrict__ W1, const float* __restrict__ biasR,
               unsigned short* __restrict__ pOut, unsigned short* __restrict__ rOut,
               int M, int job, int xt) {
    constexpr int CT = 4;
    int outSel, chalf;
    if (NOUT == 128) { outSel = job >> 1; chalf = job & 1; }
    else             { outSel = job;      chalf = 0; }
    const unsigned short* W = (outSel ? W1 : W0) + chalf * 64 * 128;

    const int wv = threadIdx.x >> 6, ln = threadIdx.x & 63;
    const int bl = ln & 15, quad = ln >> 4;
    const int mt = xt * 4 + wv;

    ABfrag Bf[CT][4];
    #pragma unroll
    for (int ct = 0; ct < CT; ++ct)
        #pragma unroll
        for (int ks = 0; ks < 4; ++ks)
            Bf[ct][ks].q = *(const uint4*)&W[(size_t)(ct * 16 + bl) * 128 + ks * 32 + quad * 8];

    if (mt * 16 >= M) return;
    const int m0 = mt * 16;
    const int arow = m0 + bl;

    floatx4 acc[CT];
    #pragma unroll
    for (int ct = 0; ct < CT; ++ct) acc[ct] = (floatx4){0.f, 0.f, 0.f, 0.f};

    #pragma unroll
    for (int ks = 0; ks < 4; ++ks) {
        ABfrag Af;
        Af.q = *(const uint4*)&A[(size_t)arow * 128 + ks * 32 + quad * 8];
        #pragma unroll
        for (int ct = 0; ct < CT; ++ct)
            acc[ct] = __builtin_amdgcn_mfma_f32_16x16x32_bf16(Af.v, Bf[ct][ks].v, acc[ct], 0, 0, 0);
    }

    unsigned short* outp = outSel ? rOut : pOut;
    #pragma unroll
    for (int ct = 0; ct < CT; ++ct) {
        int col = chalf * 64 + ct * 16 + bl;
        float bv = outSel ? biasR[col] : 0.f;
        #pragma unroll
        for (int i = 0; i < 4; ++i) {
            int row = m0 + quad * 4 + i;
            outp[(size_t)row * NOUT + col] = f2bf(acc[ct][i] + bv);
        }
    }
}

// D3: layer-1 GEMM (4 jobs via grid.y)
__global__ __launch_bounds__(THREADS)
void gemm128(const unsigned short* __restrict__ A, const unsigned short* __restrict__ W0,
             const unsigned short* __restrict__ W1, const float* __restrict__ b1,
             unsigned short* __restrict__ p1, unsigned short* __restrict__ r1, int M) {
    gemm_body<128>(A, W0, W1, b1, p1, r1, M, blockIdx.y, blockIdx.x);
}

// D6: layer-2 GEMM (2 jobs via grid.y)
__global__ __launch_bounds__(THREADS)
void gemm64(const unsigned short* __restrict__ A, const unsigned short* __restrict__ W0,
            const unsigned short* __restrict__ W1, const float* __restrict__ b2,
            unsigned short* __restrict__ p2, unsigned short* __restrict__ r2, int M) {
    gemm_body<64>(A, W0, W1, b2, p2, r2, M, blockIdx.y, blockIdx.x);
}

// ---------------------------------------------------------------------------
// D4: CSR finalize, single global pass over pairs. [R11-proven]
__global__ __launch_bounds__(THREADS)
void csr_finalize(const unsigned int* __restrict__ pairs, const unsigned int* __restrict__ counts,
                  const int* __restrict__ totals, int* __restrict__ rowptr,
                  unsigned short* __restrict__ csr, int N, int E, int NB, int chunk) {
    __shared__ unsigned int bp[BCAP];
    __shared__ unsigned short sp[BCAP];
    __shared__ int runbase[NBLK1 + 1];
    __shared__ int runsrc[NBLK1];
    __shared__ int s0arr[THREADS], lhist[THREADS], lscan[THREADS], loff[THREADS];
    __shared__ int gbs;
    int b = blockIdx.x, t = threadIdx.x;

    int tv = (t < NB) ? totals[t] : 0;
    s0arr[t] = tv;
    __syncthreads();
    for (int off = 1; off < THREADS; off <<= 1) {
        int xx = (t >= off) ? s0arr[t - off] : 0;
        __syncthreads();
        s0arr[t] += xx;
        __syncthreads();
    }
    if (t == b) gbs = s0arr[t] - tv;
    __syncthreads();

    unsigned int pc0 = counts[(size_t)t * 256 + b];
    unsigned int pc1 = counts[(size_t)(t + 256) * 256 + b];
    int c0 = (int)(pc0 & 0xffffu), c1 = (int)(pc1 & 0xffffu);
    runsrc[t] = t * chunk + (int)(pc0 >> 16);
    runsrc[t + 256] = (t + 256) * chunk + (int)(pc1 >> 16);
    s0arr[t] = c0;
    __syncthreads();
    for (int off = 1; off < THREADS; off <<= 1) {
        int xx = (t >= off) ? s0arr[t - off] : 0;
        __syncthreads();
        s0arr[t] += xx;
        __syncthreads();
    }
    runbase[t] = s0arr[t] - c0;
    int S0 = s0arr[THREADS - 1];
    __syncthreads();
    s0arr[t] = c1;
    __syncthreads();
    for (int off = 1; off < THREADS; off <<= 1) {
        int xx = (t >= off) ? s0arr[t - off] : 0;
        __syncthreads();
        s0arr[t] += xx;
        __syncthreads();
    }
    runbase[256 + t] = S0 + s0arr[t] - c1;
    if (t == THREADS - 1) runbase[512] = S0 + s0arr[t];
    __syncthreads();
    int sz = runbase[512];

    int rid = t >> 4, j0 = t & 15;
    for (int blk = rid; blk < NBLK1; blk += 16) {
        int d0 = runbase[blk];
        int len = runbase[blk + 1] - d0;
        int ss = runsrc[blk];
        for (int j = j0; j < len; j += 16) bp[d0 + j] = pairs[ss + j];
    }
    lhist[t] = 0;
    __syncthreads();

    for (int i = t; i < sz; i += THREADS) atomicAdd(&lhist[(bp[i] >> 16) & 255], 1);
    __syncthreads();
    int v = lhist[t];
    lscan[t] = v;
    __syncthreads();
    for (int off = 1; off < THREADS; off <<= 1) {
        int xx = (t >= off) ? lscan[t - off] : 0;
        __syncthreads();
        lscan[t] += xx;
        __syncthreads();
    }
    int rel = lscan[t] - v;
    int gb = gbs;
    int id = (b << 8) + t;
    if (id < N) rowptr[id] = gb + rel;
    loff[t] = rel;
    __syncthreads();

    for (int i = t; i < sz; i += THREADS) {
        unsigned int p = bp[i];
        int pos = atomicAdd(&loff[(p >> 16) & 255], 1);
        sp[pos] = (unsigned short)(p & 0xffffu);
    }
    __syncthreads();
    for (int i = t; i < sz; i += THREADS) csr[gb + i] = sp[i];
    if (b == NB - 1 && t == 0) rowptr[N] = E;
}

// ---------------------------------------------------------------------------
// D5: gather layer 1, single pass (16 lanes/node, 256B row/edge):
// h[g][:] = relu(mean p1[src][:] + r1[g][:]), bf16 in/out, fp32 accumulate.
__global__ __launch_bounds__(THREADS)
void gather_h(const unsigned short* __restrict__ p1, const int* __restrict__ rowptr,
              const unsigned short* __restrict__ csr, const unsigned short* __restrict__ r1,
              unsigned short* __restrict__ h, int N) {
    int g = blockIdx.x * 16 + (threadIdx.x >> 4);
    if (g >= N) return;
    int lane = threadIdx.x & 15;
    int start = rowptr[g], end = rowptr[g + 1];
    float acc[8] = {0.f, 0.f, 0.f, 0.f, 0.f, 0.f, 0.f, 0.f};
    int base = start;
    for (; base + 16 <= end; base += 16) {
        int sv = (int)__builtin_nontemporal_load(csr + base + lane);
        #pragma unroll
        for (int j = 0; j < 16; ++j) {
            int s = __shfl(sv, j, 16);
            acc8(acc, *(const uint4*)&p1[(size_t)s * 128 + lane * 8]);
        }
    }
    if (base < end) {
        int my = base + lane;
        int sv = (my < end) ? (int)csr[my] : 0;
        int m = end - base;
        for (int j = 0; j < m; ++j) {
            int s = __shfl(sv, j, 16);
            acc8(acc, *(const uint4*)&p1[(size_t)s * 128 + lane * 8]);
        }
    }
    float rc = 1.0f / fmaxf((float)(end - start), 1.0f);
    V4 rv;
    rv.w = __builtin_nontemporal_load((const u32x4*)(r1 + (size_t)g * 128 + lane * 8));
    float rr[8];
    unpack8(rr, rv.q);
    float o[8];
    #pragma unroll
    for (int i = 0; i < 8; ++i) o[i] = fmaxf(acc[i] * rc + rr[i], 0.f);
    u32x4 u;
    u[0] = (unsigned)f2bf(o[0]) | ((unsigned)f2bf(o[1]) << 16);
    u[1] = (unsigned)f2bf(o[2]) | ((unsigned)f2bf(o[3]) << 16);
    u[2] = (unsigned)f2bf(o[4]) | ((unsigned)f2bf(o[5]) << 16);
    u[3] = (unsigned)f2bf(o[6]) | ((unsigned)f2bf(o[7]) << 16);
    __builtin_nontemporal_store(u, (u32x4*)(h + (size_t)g * 128 + lane * 8));
}

// D7: gather layer 2 (final), single pass (8 lanes/node, 128B row/edge):
// out[g][:] = mean p2[src][:] + r2[g][:], fp32 out.
__global__ __launch_bounds__(THREADS)
void gather_out(const unsigned short* __restrict__ p2, const int* __restrict__ rowptr,
                const unsigned short* __restrict__ csr, const unsigned short* __restrict__ r2,
                float* __restrict__ out, int N) {
    int g = blockIdx.x * 32 + (threadIdx.x >> 3);
    if (g >= N) return;
    int lane = threadIdx.x & 7;
    int start = rowptr[g], end = rowptr[g + 1];
    float acc[8] = {0.f, 0.f, 0.f, 0.f, 0.f, 0.f, 0.f, 0.f};
    int base = start;
    for (; base + 8 <= end; base += 8) {
        int sv = (int)__builtin_nontemporal_load(csr + base + lane);
        #pragma unroll
        for (int j = 0; j < 8; ++j) {
            int s = __shfl(sv, j, 8);
            acc8(acc, *(const uint4*)&p2[(size_t)s * 64 + lane * 8]);
        }
    }
    if (base < end) {
        int my = base + lane;
        int sv = (my < end) ? (int)csr[my] : 0;
        int m = end - base;
        for (int j = 0; j < m; ++j) {
            int s = __shfl(sv, j, 8);
            acc8(acc, *(const uint4*)&p2[(size_t)s * 64 + lane * 8]);
        }
    }
    float rc = 1.0f / fmaxf((float)(end - start), 1.0f);
    V4 rv;
    rv.w = __builtin_nontemporal_load((const u32x4*)(r2 + (size_t)g * 64 + lane * 8));
    float rr[8];
    unpack8(rr, rv.q);
    f32x4 o0, o1;
    #pragma unroll
    for (int i = 0; i < 4; ++i) o0[i] = acc[i] * rc + rr[i];
    #pragma unroll
    for (int i = 0; i < 4; ++i) o1[i] = acc[4 + i] * rc + rr[4 + i];
    f32x4* o4 = (f32x4*)(out + (size_t)g * 64 + lane * 8);
    __builtin_nontemporal_store(o0, o4);
    __builtin_nontemporal_store(o1, o4 + 1);
}

// ---------------------------------------------------------------------------
extern "C" void kernel_launch(void* const* d_in, const int* in_sizes, int n_in,
                              void* d_out, int out_size, void* d_ws, size_t ws_size,
                              hipStream_t stream) {
    const float* x   = (const float*)d_in[0];
    const int* edges = (const int*)d_in[1];
    const float* Wl1 = (const float*)d_in[2];
    const float* Wr1 = (const float*)d_in[3];
    const float* b1  = (const float*)d_in[4];
    const float* Wl2 = (const float*)d_in[5];
    const float* Wr2 = (const float*)d_in[6];
    const float* b2  = (const float*)d_in[7];
    float* out = (float*)d_out;

    const int N = in_sizes[0] / 128;     // 50000 (< 65536)
    const int E = in_sizes[1] / 2;       // 1600000
    const int NB = (N + 255) >> 8;       // 196
    const int chunk = (E + NBLK1 - 1) / NBLK1;   // 3125
    const int* src = edges;
    const int* dstv = edges + E;

    // Workspace (row-major tables, bf16 except out)
    char* wsp = (char*)d_ws;
    unsigned short* p1  = (unsigned short*)wsp;  wsp += (size_t)N * 128 * 2;   // 12.8 MB
    unsigned short* r1  = (unsigned short*)wsp;  wsp += (size_t)N * 128 * 2;   // 12.8 MB
    unsigned short* h   = (unsigned short*)wsp;  wsp += (size_t)N * 128 * 2;   // 12.8 MB
    unsigned short* p2  = (unsigned short*)wsp;  wsp += (size_t)N * 64 * 2;    //  6.4 MB
    unsigned short* r2  = (unsigned short*)wsp;  wsp += (size_t)N * 64 * 2;    //  6.4 MB
    unsigned short* xb  = (unsigned short*)wsp;  wsp += (size_t)N * 128 * 2;   // 12.8 MB
    unsigned int* pairs = (unsigned int*)wsp;    wsp += (size_t)E * 4;         //  6.4 MB
    unsigned short* csr = (unsigned short*)wsp;  wsp += (size_t)E * 2;         //  3.2 MB
    unsigned short* Wb  = (unsigned short*)wsp;  wsp += (size_t)49152 * 2;     // 96 KB
    unsigned int* counts= (unsigned int*)wsp;    wsp += (size_t)NBLK1 * 256 * 4; // 512 KB
    int* totals         = (int*)wsp;             wsp += 256 * 4;
    int* rowptr         = (int*)wsp;             wsp += (size_t)(N + 1) * 4;

    unsigned short* Wl1b = Wb;
    unsigned short* Wr1b = Wb + 16384;
    unsigned short* Wl2b = Wb + 32768;
    unsigned short* Wr2b = Wb + 40960;

    const int nx4 = N * 128 / 4;
    const int castBlocks = (nx4 + 49152 + THREADS - 1) / THREADS;
    const int MT = (N + 15) / 16;                 // 3125
    const int gemmBlocks = (MT + 3) / 4;          // 782

    (void)hipMemsetAsync(totals, 0, 256 * sizeof(int), stream);

    // D1: cast
    cast_xw<<<castBlocks, THREADS, 0, stream>>>(x, Wl1, Wr1, Wl2, Wr2, xb, Wb, nx4);
    // D2: CSR part1
    csr_part1<<<NBLK1, THREADS, 0, stream>>>(src, dstv, pairs, counts, totals, E, chunk, NB);
    // D3: layer-1 GEMM
    gemm128<<<dim3(gemmBlocks, 4), THREADS, 0, stream>>>(xb, Wl1b, Wr1b, b1, p1, r1, N);
    // D4: CSR finalize
    csr_finalize<<<NB, THREADS, 0, stream>>>(pairs, counts, totals, rowptr, csr, N, E, NB, chunk);
    // D5: gather layer 1 (single pass)
    gather_h<<<(N + 15) / 16, THREADS, 0, stream>>>(p1, rowptr, csr, r1, h, N);
    // D6: layer-2 GEMM
    gemm64<<<dim3(gemmBlocks, 2), THREADS, 0, stream>>>(h, Wl2b, Wr2b, b2, p2, r2, N);
    // D7: gather layer 2 -> output (single pass)
    gather_out<<<(N + 31) / 32, THREADS, 0, stream>>>(p2, rowptr, csr, r2, out, N);
}

// Round 14
// 287.077 us; speedup vs baseline: 1.0827x; 1.0827x over previous
//
#include <hip/hip_runtime.h>
#include <hip/hip_bf16.h>

// GraphSAGE 2-layer forward.
// R14 = best-of composition + visibility split:
//  - R9's slab-major 4-lane gathers (48 VGPR, proven 67us) WITHOUT R12's perm
//    (perm regressed FETCH +17MB via scattered locality).
//  - R12's fused gemm128 + SINGLE-PASS csr finalize (bp LDS staging).
//  - R9's fused cast + CSR part1.
//  - r1/r2 bf16 (R13-proven numerically; -19MB vs fp32 r1).
//  - DIAGNOSTIC: gather_h split into two half (2-slab) dispatches so the
//    profiler's top-5 (always replicas of the max kernel) reveals the true
//    runner-up kernels.

#define THREADS 256
#define NBLK1 512          // csr part1 blocks (chunk = 3125 <= 3328 stage cap)
#define BCAP 12288         // finalize LDS pair capacity (bucket mean 8192)

typedef __bf16 bf16x8 __attribute__((ext_vector_type(8)));
typedef float floatx4 __attribute__((ext_vector_type(4)));
typedef float f32x4 __attribute__((ext_vector_type(4)));
typedef unsigned int u32x4 __attribute__((ext_vector_type(4)));

union ABfrag { bf16x8 v; unsigned short u[8]; uint4 q; };
union V4 { u32x4 w; uint4 q; };

static __device__ __forceinline__ unsigned short f2bf(float f) {
    unsigned int u = __float_as_uint(f);
    u = (u + 0x7fffu + ((u >> 16) & 1u)) >> 16;   // RNE
    return (unsigned short)u;
}

static __device__ __forceinline__ void unpack8(float* o, uint4 v) {
    o[0] = __uint_as_float(v.x << 16);
    o[1] = __uint_as_float(v.x & 0xffff0000u);
    o[2] = __uint_as_float(v.y << 16);
    o[3] = __uint_as_float(v.y & 0xffff0000u);
    o[4] = __uint_as_float(v.z << 16);
    o[5] = __uint_as_float(v.z & 0xffff0000u);
    o[6] = __uint_as_float(v.w << 16);
    o[7] = __uint_as_float(v.w & 0xffff0000u);
}

static __device__ __forceinline__ void acc8(float* acc, uint4 v) {
    float t[8];
    unpack8(t, v);
    #pragma unroll
    for (int i = 0; i < 8; ++i) acc[i] += t[i];
}

// ---------------------------------------------------------------------------
// D1: fused cast (x->bf16, W->bf16) + CSR part1. [R9-proven]
__global__ __launch_bounds__(THREADS)
void fused_cast_p1(const float* __restrict__ x, const float* __restrict__ wa,
                   const float* __restrict__ wb, const float* __restrict__ wc,
                   const float* __restrict__ wd, unsigned short* __restrict__ xb,
                   unsigned short* __restrict__ Wb, int nx4,
                   const int* __restrict__ src, const int* __restrict__ dst,
                   unsigned int* __restrict__ pairs, unsigned int* __restrict__ counts,
                   int* __restrict__ totals, int E, int chunk, int NB) {
    __shared__ int lh[THREADS], lsc[THREADS], lpos[THREADS];
    __shared__ unsigned int stage[3328];
    int t = threadIdx.x;
    if (blockIdx.x < NBLK1) {
        int e0 = blockIdx.x * chunk, e1 = min(E, e0 + chunk);
        lh[t] = 0;
        __syncthreads();
        for (int e = e0 + t; e < e1; e += THREADS) atomicAdd(&lh[dst[e] >> 8], 1);
        __syncthreads();
        int v = lh[t];
        lsc[t] = v;
        __syncthreads();
        for (int off = 1; off < THREADS; off <<= 1) {
            int tv = (t >= off) ? lsc[t - off] : 0;
            __syncthreads();
            lsc[t] += tv;
            __syncthreads();
        }
        int base = lsc[t] - v;
        lpos[t] = base;
        __syncthreads();
        for (int e = e0 + t; e < e1; e += THREADS) {
            int dd = dst[e];
            int p = atomicAdd(&lpos[dd >> 8], 1);
            stage[p] = (unsigned int)src[e] | ((unsigned int)(dd & 255) << 16);
        }
        __syncthreads();
        int n = e1 - e0;
        for (int i = t; i < n; i += THREADS) pairs[e0 + i] = stage[i];
        if (t < NB) {
            counts[(size_t)blockIdx.x * 256 + t] = ((unsigned int)base << 16) | (unsigned int)v;
            if (v) atomicAdd(&totals[t], v);
        }
        return;
    }
    int i = (blockIdx.x - NBLK1) * THREADS + t;
    if (i < nx4) {
        float4 v = ((const float4*)x)[i];
        ushort4 u;
        u.x = f2bf(v.x); u.y = f2bf(v.y); u.z = f2bf(v.z); u.w = f2bf(v.w);
        ((ushort4*)xb)[i] = u;
        return;
    }
    int j = i - nx4;
    if (j >= 49152) return;
    float v;
    if (j < 16384) v = wa[j];
    else if (j < 32768) v = wb[j - 16384];
    else if (j < 40960) v = wc[j - 32768];
    else v = wd[j - 40960];
    Wb[j] = f2bf(v);
}

// ---------------------------------------------------------------------------
// MFMA bf16 GEMM body (R9-proven): one wave per 16-row M-tile, K=128, 64 cols
// per job, B-frags VGPR-resident from pre-cast bf16 W. Outputs slab-major
// [col>>5][row][32], ALL bf16. NOUT=128: jobs 0,1 -> p halves; 2,3 -> r
// halves. NOUT=64: job 0 -> p, 1 -> r. ASLAB: A bf16 [ks][row][32].
template<int NOUT, bool ASLAB>
static __device__ __forceinline__
void gemm_body(const unsigned short* __restrict__ A, const unsigned short* __restrict__ W0,
               const unsigned short* __restrict__ W1, const float* __restrict__ biasR,
               unsigned short* __restrict__ pOut, unsigned short* __restrict__ rOut,
               int M, int job, int xt) {
    constexpr int CT = 4;
    int outSel, chalf;
    if (NOUT == 128) { outSel = job >> 1; chalf = job & 1; }
    else             { outSel = job;      chalf = 0; }
    const unsigned short* W = (outSel ? W1 : W0) + chalf * 64 * 128;

    const int wv = threadIdx.x >> 6, ln = threadIdx.x & 63;
    const int bl = ln & 15, quad = ln >> 4;
    const int mt = xt * 4 + wv;
    const size_t M32 = (size_t)M * 32;

    ABfrag Bf[CT][4];
    #pragma unroll
    for (int ct = 0; ct < CT; ++ct)
        #pragma unroll
        for (int ks = 0; ks < 4; ++ks)
            Bf[ct][ks].q = *(const uint4*)&W[(size_t)(ct * 16 + bl) * 128 + ks * 32 + quad * 8];

    if (mt * 16 >= M) return;
    const int m0 = mt * 16;
    const int arow = m0 + bl;

    floatx4 acc[CT];
    #pragma unroll
    for (int ct = 0; ct < CT; ++ct) acc[ct] = (floatx4){0.f, 0.f, 0.f, 0.f};

    #pragma unroll
    for (int ks = 0; ks < 4; ++ks) {
        ABfrag Af;
        if (ASLAB) Af.q = *(const uint4*)&A[(size_t)ks * M32 + (size_t)arow * 32 + quad * 8];
        else       Af.q = *(const uint4*)&A[(size_t)arow * 128 + ks * 32 + quad * 8];
        #pragma unroll
        for (int ct = 0; ct < CT; ++ct)
            acc[ct] = __builtin_amdgcn_mfma_f32_16x16x32_bf16(Af.v, Bf[ct][ks].v, acc[ct], 0, 0, 0);
    }

    unsigned short* outp = outSel ? rOut : pOut;
    #pragma unroll
    for (int ct = 0; ct < CT; ++ct) {
        int col = chalf * 64 + ct * 16 + bl;
        int slab = col >> 5, wi = col & 31;
        size_t sbase = (size_t)slab * M32;
        float bv = outSel ? biasR[col] : 0.f;
        #pragma unroll
        for (int i = 0; i < 4; ++i) {
            int row = m0 + quad * 4 + i;
            outp[sbase + (size_t)row * 32 + wi] = f2bf(acc[ct][i] + bv);
        }
    }
}

// ---------------------------------------------------------------------------
// D2: fused layer-1 GEMM + SINGLE-PASS CSR finalize.
// grid (gemmBlocks, 5): y>=1 -> gemm job y-1; y==0 && x<NB -> finalize.
__global__ __launch_bounds__(THREADS)
void gemm128_csr(const unsigned short* __restrict__ A, const unsigned short* __restrict__ W0,
                 const unsigned short* __restrict__ W1, const float* __restrict__ biasR,
                 unsigned short* __restrict__ pOut, unsigned short* __restrict__ rOut, int M,
                 const unsigned int* __restrict__ pairs, const unsigned int* __restrict__ counts,
                 const int* __restrict__ totals, int* __restrict__ rowptr,
                 unsigned short* __restrict__ csr, int N, int E, int NB, int chunk) {
    __shared__ unsigned int bp[BCAP];
    __shared__ int runbase[NBLK1 + 1];
    __shared__ int runsrc[NBLK1];
    __shared__ int s0arr[THREADS], lhist[THREADS], lscan[THREADS], loff[THREADS];
    __shared__ int gbs;

    if (blockIdx.y != 0) {
        gemm_body<128, false>(A, W0, W1, biasR, pOut, rOut, M, blockIdx.y - 1, blockIdx.x);
        return;
    }
    int b = blockIdx.x, t = threadIdx.x;
    if (b >= NB) return;

    // bucket base = exclusive prefix of totals
    int tv = (t < NB) ? totals[t] : 0;
    s0arr[t] = tv;
    __syncthreads();
    for (int off = 1; off < THREADS; off <<= 1) {
        int xx = (t >= off) ? s0arr[t - off] : 0;
        __syncthreads();
        s0arr[t] += xx;
        __syncthreads();
    }
    if (t == b) gbs = s0arr[t] - tv;
    __syncthreads();

    // run bases: scan 512 run lengths (2 per thread)
    unsigned int pc0 = counts[(size_t)t * 256 + b];
    unsigned int pc1 = counts[(size_t)(t + 256) * 256 + b];
    int c0 = (int)(pc0 & 0xffffu), c1 = (int)(pc1 & 0xffffu);
    runsrc[t] = t * chunk + (int)(pc0 >> 16);
    runsrc[t + 256] = (t + 256) * chunk + (int)(pc1 >> 16);
    s0arr[t] = c0;
    __syncthreads();
    for (int off = 1; off < THREADS; off <<= 1) {
        int xx = (t >= off) ? s0arr[t - off] : 0;
        __syncthreads();
        s0arr[t] += xx;
        __syncthreads();
    }
    runbase[t] = s0arr[t] - c0;
    int S0 = s0arr[THREADS - 1];
    __syncthreads();
    s0arr[t] = c1;
    __syncthreads();
    for (int off = 1; off < THREADS; off <<= 1) {
        int xx = (t >= off) ? s0arr[t - off] : 0;
        __syncthreads();
        s0arr[t] += xx;
        __syncthreads();
    }
    runbase[256 + t] = S0 + s0arr[t] - c1;
    if (t == THREADS - 1) runbase[512] = S0 + s0arr[t];
    __syncthreads();
    int sz = runbase[512];

    // ONE global pass: 16 threads per run, coalesced copy into LDS
    int rid = t >> 4, j0 = t & 15;
    for (int blk = rid; blk < NBLK1; blk += 16) {
        int d0 = runbase[blk];
        int len = runbase[blk + 1] - d0;
        int ss = runsrc[blk];
        for (int j = j0; j < len; j += 16) bp[d0 + j] = pairs[ss + j];
    }
    lhist[t] = 0;
    __syncthreads();

    // LDS hist + scan -> rowptr
    for (int i = t; i < sz; i += THREADS) atomicAdd(&lhist[(bp[i] >> 16) & 255], 1);
    __syncthreads();
    int v = lhist[t];
    lscan[t] = v;
    __syncthreads();
    for (int off = 1; off < THREADS; off <<= 1) {
        int xx = (t >= off) ? lscan[t - off] : 0;
        __syncthreads();
        lscan[t] += xx;
        __syncthreads();
    }
    int rel = lscan[t] - v;
    int gb = gbs;
    int id = (b << 8) + t;
    if (id < N) rowptr[id] = gb + rel;
    loff[t] = gb + rel;
    __syncthreads();

    // direct scatter to global csr (exclusive ~16KB window, L2 assembles lines)
    for (int i = t; i < sz; i += THREADS) {
        unsigned int p = bp[i];
        int pos = atomicAdd(&loff[(p >> 16) & 255], 1);
        csr[pos] = (unsigned short)(p & 0xffffu);
    }
    if (b == NB - 1 && t == 0) rowptr[N] = E;
}

// D4: layer-2 GEMM (A = h bf16 slab-major, W bf16 pre-cast). 2 jobs via grid.y.
__global__ __launch_bounds__(THREADS)
void gemm64(const unsigned short* __restrict__ A, const unsigned short* __restrict__ W0,
            const unsigned short* __restrict__ W1, const float* __restrict__ b2,
            unsigned short* __restrict__ p2, unsigned short* __restrict__ r2, int M) {
    gemm_body<64, true>(A, W0, W1, b2, p2, r2, M, blockIdx.y, blockIdx.x);
}

// ---------------------------------------------------------------------------
// D3a/D3b: slabbed gather layer 1 (R9 structure, 4 lanes/node, 48 VGPR):
// h[s][g][:] = relu(mean p1[s][src][:] + r1[s][g][:]), bf16 tables/out.
// slabBase selects which 2-slab half this dispatch covers (diagnostic split).
__global__ __launch_bounds__(THREADS)
void gather_h(const unsigned short* __restrict__ p1, const int* __restrict__ rowptr,
              const unsigned short* __restrict__ csr, const unsigned short* __restrict__ r1,
              unsigned short* __restrict__ h, int N, int nodeBlocks, int slabBase) {
    const size_t N32 = (size_t)N * 32;
    int slab = slabBase + blockIdx.x / nodeBlocks;
    int nb = blockIdx.x - (slab - slabBase) * nodeBlocks;
    int g = nb * 64 + (threadIdx.x >> 2);
    if (g >= N) return;
    int lane = threadIdx.x & 3;
    const unsigned short* ps = p1 + slab * N32;
    int start = rowptr[g], end = rowptr[g + 1];
    float acc[8] = {0.f, 0.f, 0.f, 0.f, 0.f, 0.f, 0.f, 0.f};
    int base = start;
    for (; base + 8 <= end; base += 8) {
        int sv0 = (int)__builtin_nontemporal_load(csr + base + lane);
        int sv1 = (int)__builtin_nontemporal_load(csr + base + 4 + lane);
        #pragma unroll
        for (int j = 0; j < 8; ++j) {
            int s = __shfl(j < 4 ? sv0 : sv1, j & 3, 4);
            acc8(acc, *(const uint4*)&ps[(size_t)s * 32 + lane * 8]);
        }
    }
    for (; base + 4 <= end; base += 4) {
        int sv = (int)__builtin_nontemporal_load(csr + base + lane);
        #pragma unroll
        for (int j = 0; j < 4; ++j) {
            int s = __shfl(sv, j, 4);
            acc8(acc, *(const uint4*)&ps[(size_t)s * 32 + lane * 8]);
        }
    }
    if (base < end) {
        int my = base + lane;
        int sv = (my < end) ? (int)csr[my] : 0;
        int m = end - base;
        for (int j = 0; j < m; ++j) {
            int s = __shfl(sv, j, 4);
            acc8(acc, *(const uint4*)&ps[(size_t)s * 32 + lane * 8]);
        }
    }
    float rc = 1.0f / fmaxf((float)(end - start), 1.0f);
    V4 rv;
    rv.w = __builtin_nontemporal_load((const u32x4*)(r1 + slab * N32 + (size_t)g * 32 + lane * 8));
    float rr[8];
    unpack8(rr, rv.q);
    float o[8];
    #pragma unroll
    for (int i = 0; i < 8; ++i) o[i] = fmaxf(acc[i] * rc + rr[i], 0.f);
    u32x4 u;
    u[0] = (unsigned)f2bf(o[0]) | ((unsigned)f2bf(o[1]) << 16);
    u[1] = (unsigned)f2bf(o[2]) | ((unsigned)f2bf(o[3]) << 16);
    u[2] = (unsigned)f2bf(o[4]) | ((unsigned)f2bf(o[5]) << 16);
    u[3] = (unsigned)f2bf(o[6]) | ((unsigned)f2bf(o[7]) << 16);
    __builtin_nontemporal_store(u, (u32x4*)(h + slab * N32 + (size_t)g * 32 + lane * 8));
}

// D5: slabbed gather layer 2 (final): out[g][s*32+d] = mean p2[s][src][d] + r2[s][g][d]
__global__ __launch_bounds__(THREADS)
void gather_out(const unsigned short* __restrict__ p2, const int* __restrict__ rowptr,
                const unsigned short* __restrict__ csr, const unsigned short* __restrict__ r2,
                float* __restrict__ out, int N, int nodeBlocks) {
    const size_t N32 = (size_t)N * 32;
    int slab = blockIdx.x / nodeBlocks;
    int nb = blockIdx.x - slab * nodeBlocks;
    int g = nb * 64 + (threadIdx.x >> 2);
    if (g >= N) return;
    int lane = threadIdx.x & 3;
    const unsigned short* ps = p2 + slab * N32;
    int start = rowptr[g], end = rowptr[g + 1];
    float acc[8] = {0.f, 0.f, 0.f, 0.f, 0.f, 0.f, 0.f, 0.f};
    int base = start;
    for (; base + 8 <= end; base += 8) {
        int sv0 = (int)__builtin_nontemporal_load(csr + base + lane);
        int sv1 = (int)__builtin_nontemporal_load(csr + base + 4 + lane);
        #pragma unroll
        for (int j = 0; j < 8; ++j) {
            int s = __shfl(j < 4 ? sv0 : sv1, j & 3, 4);
            acc8(acc, *(const uint4*)&ps[(size_t)s * 32 + lane * 8]);
        }
    }
    for (; base + 4 <= end; base += 4) {
        int sv = (int)__builtin_nontemporal_load(csr + base + lane);
        #pragma unroll
        for (int j = 0; j < 4; ++j) {
            int s = __shfl(sv, j, 4);
            acc8(acc, *(const uint4*)&ps[(size_t)s * 32 + lane * 8]);
        }
    }
    if (base < end) {
        int my = base + lane;
        int sv = (my < end) ? (int)csr[my] : 0;
        int m = end - base;
        for (int j = 0; j < m; ++j) {
            int s = __shfl(sv, j, 4);
            acc8(acc, *(const uint4*)&ps[(size_t)s * 32 + lane * 8]);
        }
    }
    float rc = 1.0f / fmaxf((float)(end - start), 1.0f);
    V4 rv;
    rv.w = __builtin_nontemporal_load((const u32x4*)(r2 + slab * N32 + (size_t)g * 32 + lane * 8));
    float rr[8];
    unpack8(rr, rv.q);
    f32x4 o0, o1;
    #pragma unroll
    for (int i = 0; i < 4; ++i) o0[i] = acc[i] * rc + rr[i];
    #pragma unroll
    for (int i = 0; i < 4; ++i) o1[i] = acc[4 + i] * rc + rr[4 + i];
    f32x4* o4 = (f32x4*)(out + (size_t)g * 64 + slab * 32 + lane * 8);
    __builtin_nontemporal_store(o0, o4);
    __builtin_nontemporal_store(o1, o4 + 1);
}

// ---------------------------------------------------------------------------
extern "C" void kernel_launch(void* const* d_in, const int* in_sizes, int n_in,
                              void* d_out, int out_size, void* d_ws, size_t ws_size,
                              hipStream_t stream) {
    const float* x   = (const float*)d_in[0];
    const int* edges = (const int*)d_in[1];
    const float* Wl1 = (const float*)d_in[2];
    const float* Wr1 = (const float*)d_in[3];
    const float* b1  = (const float*)d_in[4];
    const float* Wl2 = (const float*)d_in[5];
    const float* Wr2 = (const float*)d_in[6];
    const float* b2  = (const float*)d_in[7];
    float* out = (float*)d_out;

    const int N = in_sizes[0] / 128;     // 50000 (< 65536)
    const int E = in_sizes[1] / 2;       // 1600000
    const int NB = (N + 255) >> 8;       // 196
    const int chunk = (E + NBLK1 - 1) / NBLK1;   // 3125
    const int* src = edges;
    const int* dstv = edges + E;

    // Workspace (slab-major tables [slab][node][32], all bf16 except out)
    char* wsp = (char*)d_ws;
    unsigned short* p1  = (unsigned short*)wsp;  wsp += (size_t)N * 128 * 2;   // 12.8 MB
    unsigned short* r1  = (unsigned short*)wsp;  wsp += (size_t)N * 128 * 2;   // 12.8 MB
    unsigned short* h   = (unsigned short*)wsp;  wsp += (size_t)N * 128 * 2;   // 12.8 MB
    unsigned short* p2  = (unsigned short*)wsp;  wsp += (size_t)N * 64 * 2;    //  6.4 MB
    unsigned short* r2  = (unsigned short*)wsp;  wsp += (size_t)N * 64 * 2;    //  6.4 MB
    unsigned short* xb  = (unsigned short*)wsp;  wsp += (size_t)N * 128 * 2;   // 12.8 MB
    unsigned int* pairs = (unsigned int*)wsp;    wsp += (size_t)E * 4;         //  6.4 MB
    unsigned short* csr = (unsigned short*)wsp;  wsp += (size_t)E * 2;         //  3.2 MB
    unsigned short* Wb  = (unsigned short*)wsp;  wsp += (size_t)49152 * 2;     // 96 KB
    unsigned int* counts= (unsigned int*)wsp;    wsp += (size_t)NBLK1 * 256 * 4; // 512 KB
    int* totals         = (int*)wsp;             wsp += 256 * 4;
    int* rowptr         = (int*)wsp;             wsp += (size_t)(N + 1) * 4;

    unsigned short* Wl1b = Wb;
    unsigned short* Wr1b = Wb + 16384;
    unsigned short* Wl2b = Wb + 32768;
    unsigned short* Wr2b = Wb + 40960;

    const int nx4 = N * 128 / 4;
    const int castBlocks = (nx4 + 49152 + THREADS - 1) / THREADS;
    const int MT = (N + 15) / 16;                 // 3125
    const int gemmBlocks = (MT + 3) / 4;          // 782
    const int nodeBlocks = (N + 63) / 64;         // 782

    (void)hipMemsetAsync(totals, 0, 256 * sizeof(int), stream);

    // D1: fused cast + CSR part1
    fused_cast_p1<<<NBLK1 + castBlocks, THREADS, 0, stream>>>(
        x, Wl1, Wr1, Wl2, Wr2, xb, Wb, nx4, src, dstv, pairs, counts, totals, E, chunk, NB);

    // D2: layer-1 GEMM (4 jobs) + single-pass CSR finalize (y==0)
    gemm128_csr<<<dim3(gemmBlocks, 5), THREADS, 0, stream>>>(
        xb, Wl1b, Wr1b, b1, p1, r1, N,
        pairs, counts, totals, rowptr, csr, N, E, NB, chunk);

    // D3a/D3b: gather layer 1, split into two 2-slab halves (diagnostic)
    gather_h<<<2 * nodeBlocks, THREADS, 0, stream>>>(p1, rowptr, csr, r1, h, N, nodeBlocks, 0);
    gather_h<<<2 * nodeBlocks, THREADS, 0, stream>>>(p1, rowptr, csr, r1, h, N, nodeBlocks, 2);

    // D4: layer-2 GEMM
    gemm64<<<dim3(gemmBlocks, 2), THREADS, 0, stream>>>(h, Wl2b, Wr2b, b2, p2, r2, N);

    // D5: gather layer 2 -> final output
    gather_out<<<2 * nodeBlocks, THREADS, 0, stream>>>(p2, rowptr, csr, r2, out, N, nodeBlocks);
}